// Round 7
// baseline (160.350 us; speedup 1.0000x reference)
//
#include <hip/hip_runtime.h>
#include <cstdint>
#include <cstddef>

#define MROWS 1024
#define NCOLS 4096
#define TOPK 16

typedef unsigned long long u64;
typedef unsigned int u32;

// Order-preserving float->u32 map (total order, matches score order exactly).
__device__ inline u32 fkey(u32 b) { return (b & 0x80000000u) ? ~b : (b | 0x80000000u); }

// key = (ord << 22) | ((1023-row) << 12) | (4095-col)   (54 bits used)
__device__ inline int key_col(u64 k) { return (NCOLS - 1) - (int)(k & 0xFFFull); }
__device__ inline int key_row(u64 k) { return (MROWS - 1) - (int)((k >> 12) & 0x3FFull); }

// single-wave LDS ordering fence: wait LDS only, do NOT drain vmcnt
#define WAVE_FENCE() __asm__ volatile("s_waitcnt lgkmcnt(0)" ::: "memory")

__device__ inline float wave_sum_f(float v) {
    #pragma unroll
    for (int off = 32; off >= 1; off >>= 1)
        v += __shfl_xor(v, off, 64);
    return v;
}
__device__ inline u64 wave_max_u64(u64 v) {
    #pragma unroll
    for (int off = 32; off >= 1; off >>= 1) {
        u64 o = __shfl_xor(v, off, 64);
        v = o > v ? o : v;
    }
    return v;
}
__device__ inline u64 umax64(u64 a, u64 b) { return a > b ? a : b; }

// ---- compare-exchange on NAMED scalars (registers guaranteed) --------------
#define CED(x, y) do { u64 _mx = (x) > (y) ? (x) : (y); \
                       u64 _mn = (x) > (y) ? (y) : (x); (x) = _mx; (y) = _mn; } while (0)
#define CEA(x, y) CED(y, x)

// bitonic sort-8 descending on a0..a7
#define SORT8D \
    CED(a0,a1); CEA(a2,a3); CED(a0,a2); CED(a1,a3); CED(a0,a1); CED(a2,a3); \
    CEA(a4,a5); CED(a6,a7); CEA(a4,a6); CEA(a5,a7); CEA(a4,a5); CEA(a6,a7); \
    CED(a0,a4); CED(a1,a5); CED(a2,a6); CED(a3,a7); \
    CED(a0,a2); CED(a1,a3); CED(a4,a6); CED(a5,a7); \
    CED(a0,a1); CED(a2,a3); CED(a4,a5); CED(a6,a7);

// bitonic merge-16 descending (input bitonic in a0..a15)
#define BMERGE16D \
    CED(a0,a8); CED(a1,a9); CED(a2,a10); CED(a3,a11); CED(a4,a12); CED(a5,a13); CED(a6,a14); CED(a7,a15); \
    CED(a0,a4); CED(a1,a5); CED(a2,a6);  CED(a3,a7);  CED(a8,a12); CED(a9,a13); CED(a10,a14); CED(a11,a15); \
    CED(a0,a2); CED(a1,a3); CED(a4,a6);  CED(a5,a7);  CED(a8,a10); CED(a9,a11); CED(a12,a14); CED(a13,a15); \
    CED(a0,a1); CED(a2,a3); CED(a4,a5);  CED(a6,a7);  CED(a8,a9);  CED(a10,a11); CED(a12,a13); CED(a14,a15);

// top-16 of two descending-sorted 16-lists (a, b) -> bitonic in a
#define HALFCLEAN \
    a0 = umax64(a0,b15); a1 = umax64(a1,b14); a2 = umax64(a2,b13); a3 = umax64(a3,b12); \
    a4 = umax64(a4,b11); a5 = umax64(a5,b10); a6 = umax64(a6,b9);  a7 = umax64(a7,b8);  \
    a8 = umax64(a8,b7);  a9 = umax64(a9,b6);  a10 = umax64(a10,b5); a11 = umax64(a11,b4); \
    a12 = umax64(a12,b3); a13 = umax64(a13,b2); a14 = umax64(a14,b1); a15 = umax64(a15,b0);

#define ST16(idx) \
    buf16[0*256+(idx)]=a0; buf16[1*256+(idx)]=a1; buf16[2*256+(idx)]=a2; buf16[3*256+(idx)]=a3; \
    buf16[4*256+(idx)]=a4; buf16[5*256+(idx)]=a5; buf16[6*256+(idx)]=a6; buf16[7*256+(idx)]=a7; \
    buf16[8*256+(idx)]=a8; buf16[9*256+(idx)]=a9; buf16[10*256+(idx)]=a10; buf16[11*256+(idx)]=a11; \
    buf16[12*256+(idx)]=a12; buf16[13*256+(idx)]=a13; buf16[14*256+(idx)]=a14; buf16[15*256+(idx)]=a15;

#define LD16B(idx) \
    b0=buf16[0*256+(idx)]; b1=buf16[1*256+(idx)]; b2=buf16[2*256+(idx)]; b3=buf16[3*256+(idx)]; \
    b4=buf16[4*256+(idx)]; b5=buf16[5*256+(idx)]; b6=buf16[6*256+(idx)]; b7=buf16[7*256+(idx)]; \
    b8=buf16[8*256+(idx)]; b9=buf16[9*256+(idx)]; b10=buf16[10*256+(idx)]; b11=buf16[11*256+(idx)]; \
    b12=buf16[12*256+(idx)]; b13=buf16[13*256+(idx)]; b14=buf16[14*256+(idx)]; b15=buf16[15*256+(idx)];

#define MERGE16(idx) LD16B(idx); HALFCLEAN; BMERGE16D;

// ---------------- K1: per-row exp-sum only (trivial streaming pass) -----------
__global__ __launch_bounds__(256) void k_rowsum(const float* __restrict__ s,
                                                float* __restrict__ rowsum) {
    __shared__ float fred[4];
    int r = blockIdx.x, t = threadIdx.x;
    const float4* s4 = (const float4*)(s + (size_t)r * NCOLS);
    float4 v0 = s4[t], v1 = s4[t + 256], v2 = s4[t + 512], v3 = s4[t + 768];
    float acc;
    acc  = __expf(v0.x) + __expf(v0.y) + __expf(v0.z) + __expf(v0.w);
    acc += __expf(v1.x) + __expf(v1.y) + __expf(v1.z) + __expf(v1.w);
    acc += __expf(v2.x) + __expf(v2.y) + __expf(v2.z) + __expf(v2.w);
    acc += __expf(v3.x) + __expf(v3.y) + __expf(v3.z) + __expf(v3.w);
    acc = wave_sum_f(acc);
    if ((t & 63) == 0) fred[t >> 6] = acc;
    __syncthreads();
    if (t == 0) rowsum[r] = fred[0] + fred[1] + fred[2] + fred[3];
}

// Batched prune: all 16 coldone word-loads independent, then registers-only.
__device__ inline u64 prune_and_best(u64* kk, const u32* coldone) {
    u32 cw[TOPK];
    #pragma unroll
    for (int k = 0; k < TOPK; ++k) {
        int c = key_col(kk[k]);          // dead key -> col 4095, harmless read
        cw[k] = coldone[c >> 5];
    }
    u64 best = 0ull;
    #pragma unroll
    for (int k = 0; k < TOPK; ++k) {
        int c = key_col(kk[k]);
        if ((cw[k] >> (c & 31)) & 1u) kk[k] = 0ull;
        best = umax64(best, kk[k]);
    }
    return best;
}

// ---------------- K2: block 0 = match (spins for keys); blocks 1..1024 =
// policy + per-row top-16 keys (sorted-8 per thread + LDS merge tree).
// Producer-consumer: worker writes keys -> threadfence -> ready++. Only block 0
// spins, and it depends only on blocks that depend on nothing -> deadlock-free
// for any dispatch order / occupancy (capacity >= 2). ready check is >=1024 so
// rocprof single-dispatch replay (stale counter) is safe.
__global__ __launch_bounds__(512, 2) void k_main(const float* __restrict__ s,
                                                 const int* __restrict__ cont,
                                                 const int* __restrict__ prev,
                                                 const float* __restrict__ rowsum,
                                                 u32* __restrict__ ready,
                                                 u64* __restrict__ keys_g,
                                                 float* __restrict__ policy,
                                                 float* __restrict__ actions) {
    __shared__ __align__(16) char smem[65536];
    int t = threadIdx.x;

    if (blockIdx.x != 0) {
        // ---------------- worker: keys first (unblocks match), then policy ----
        u64* buf8  = (u64*)smem;             // [8][512]  = 32 KiB
        u64* buf16 = (u64*)(smem + 32768);   // [16][256] = 32 KiB
        int r = blockIdx.x - 1;
        const float4* s4 = (const float4*)(s + (size_t)r * NCOLS);
        float4 v0 = s4[t], v1 = s4[t + 512];
        u64 rowpart = (u64)(MROWS - 1 - r) << 12;
        u64 a0,a1,a2,a3,a4,a5,a6,a7,a8,a9,a10,a11,a12,a13,a14,a15;
        u64 b0,b1,b2,b3,b4,b5,b6,b7,b8,b9,b10,b11,b12,b13,b14,b15;
        {
            int c0 = 4 * t, c1 = 4 * (t + 512);
            a0 = ((u64)fkey(__float_as_uint(v0.x)) << 22) | rowpart | (u64)(NCOLS - 1 - (c0 + 0));
            a1 = ((u64)fkey(__float_as_uint(v0.y)) << 22) | rowpart | (u64)(NCOLS - 1 - (c0 + 1));
            a2 = ((u64)fkey(__float_as_uint(v0.z)) << 22) | rowpart | (u64)(NCOLS - 1 - (c0 + 2));
            a3 = ((u64)fkey(__float_as_uint(v0.w)) << 22) | rowpart | (u64)(NCOLS - 1 - (c0 + 3));
            a4 = ((u64)fkey(__float_as_uint(v1.x)) << 22) | rowpart | (u64)(NCOLS - 1 - (c1 + 0));
            a5 = ((u64)fkey(__float_as_uint(v1.y)) << 22) | rowpart | (u64)(NCOLS - 1 - (c1 + 1));
            a6 = ((u64)fkey(__float_as_uint(v1.z)) << 22) | rowpart | (u64)(NCOLS - 1 - (c1 + 2));
            a7 = ((u64)fkey(__float_as_uint(v1.w)) << 22) | rowpart | (u64)(NCOLS - 1 - (c1 + 3));
        }
        SORT8D;                               // my 8 keys, descending
        buf8[0*512+t]=a0; buf8[1*512+t]=a1; buf8[2*512+t]=a2; buf8[3*512+t]=a3;
        buf8[4*512+t]=a4; buf8[5*512+t]=a5; buf8[6*512+t]=a6; buf8[7*512+t]=a7;
        __syncthreads();
        if (t < 256) {                        // merge sorted-8 pairs -> sorted-16
            int u = t + 256;
            a8  = buf8[7*512+u]; a9  = buf8[6*512+u]; a10 = buf8[5*512+u]; a11 = buf8[4*512+u];
            a12 = buf8[3*512+u]; a13 = buf8[2*512+u]; a14 = buf8[1*512+u]; a15 = buf8[0*512+u];
            BMERGE16D;                        // desc ++ reversed-desc = bitonic
            ST16(t);
        }
        __syncthreads();
        if (t < 128) { MERGE16(t + 128); ST16(t); }
        __syncthreads();
        if (t < 64) {
            MERGE16(t + 64); ST16(t);
            WAVE_FENCE();
            if (t < 32) { MERGE16(t + 32); ST16(t); } WAVE_FENCE();
            if (t < 16) { MERGE16(t + 16); ST16(t); } WAVE_FENCE();
            if (t < 8)  { MERGE16(t + 8);  ST16(t); } WAVE_FENCE();
            if (t < 4)  { MERGE16(t + 4);  ST16(t); } WAVE_FENCE();
            if (t < 2)  { MERGE16(t + 2);  ST16(t); } WAVE_FENCE();
            if (t == 0) {
                MERGE16(1);
                u64* ok = keys_g + (size_t)r * TOPK;
                ok[0]=a0; ok[1]=a1; ok[2]=a2; ok[3]=a3; ok[4]=a4; ok[5]=a5; ok[6]=a6; ok[7]=a7;
                ok[8]=a8; ok[9]=a9; ok[10]=a10; ok[11]=a11; ok[12]=a12; ok[13]=a13; ok[14]=a14; ok[15]=a15;
                __threadfence();
                __hip_atomic_fetch_add(ready, 1u, __ATOMIC_RELEASE, __HIP_MEMORY_SCOPE_AGENT);
            }
        }
        __syncthreads();
        // ---------------- policy (row regs still live) ------------------------
        float* fredf = (float*)smem;          // tree data dead
        float sv = rowsum[t] + rowsum[t + 512];
        sv = wave_sum_f(sv);
        if ((t & 63) == 0) fredf[t >> 6] = sv;
        __syncthreads();
        float g = 0.0f;
        #pragma unroll
        for (int i = 0; i < 8; ++i) g += fredf[i];   // same order every block
        float inv = 1.0f / g;
        float4* prow4 = (float4*)(policy + (size_t)r * NCOLS);
        float4 p;
        p.x = __expf(v0.x) * inv; p.y = __expf(v0.y) * inv;
        p.z = __expf(v0.z) * inv; p.w = __expf(v0.w) * inv;
        prow4[t] = p;
        p.x = __expf(v1.x) * inv; p.y = __expf(v1.y) * inv;
        p.z = __expf(v1.z) * inv; p.w = __expf(v1.w) * inv;
        prow4[t + 512] = p;
        return;
    }

    // ---------------- match: block 0 --------------------------------------
    u64* colbest = (u64*)smem;                 // 32 KiB
    u32* coldone = (u32*)(smem + 32768);       // 512 B
    u32* rowdone = (u32*)(smem + 33280);       // 128 B
    float* act   = (float*)(smem + 33408);     // 4 KiB

    if (t == 0) {                               // wait for all 1024 key rows
        for (long i = 0; i < 2000000000L; ++i) {
            if (__hip_atomic_load(ready, __ATOMIC_ACQUIRE, __HIP_MEMORY_SCOPE_AGENT) >= MROWS)
                break;
            __builtin_amdgcn_s_sleep(1);
        }
    }
    __syncthreads();

    #pragma unroll
    for (int i = 0; i < 8; ++i) colbest[t + i * 512] = 0ull;
    if (t < 128) coldone[t] = 0u;
    if (t < 32) rowdone[t] = 0u;
    __syncthreads();   // zeroing ordered before the atomics below

    int r0 = t, r1 = t + 512;
    int c0f = cont[r0], c1f = cont[r1];
    int p0 = prev[r0], p1 = prev[r1];
    act[r0] = c0f ? (float)p0 : -1.0f;
    act[r1] = c1f ? (float)p1 : -1.0f;
    if (c0f) {
        atomicOr(&rowdone[r0 >> 5], 1u << (r0 & 31));
        atomicOr(&coldone[p0 >> 5], 1u << (p0 & 31));
    }
    if (c1f) {
        atomicOr(&rowdone[r1 >> 5], 1u << (r1 & 31));
        atomicOr(&coldone[p1 >> 5], 1u << (p1 & 31));
    }
    bool act0 = (c0f == 0), act1 = (c1f == 0);

    u64 k0[TOPK], k1[TOPK];
    {
        const u64* g0 = keys_g + (size_t)r0 * TOPK;
        const u64* g1 = keys_g + (size_t)r1 * TOPK;
        #pragma unroll
        for (int k = 0; k < TOPK; ++k) { k0[k] = g0[k]; k1[k] = g1[k]; }
    }
    __syncthreads();

    for (int round = 1; round < 400; ++round) {
        u64 tag = (u64)round << 54;
        bool sub0 = false, sub1 = false;
        u64 best0 = 0ull, best1 = 0ull;
        if (act0) {
            best0 = prune_and_best(k0, coldone);
            if (best0 == 0ull) act0 = false;      // exhausted -> fallback later
            else {
                sub0 = true;
                #pragma unroll
                for (int k = 0; k < TOPK; ++k)
                    if (k0[k] != 0ull)
                        atomicMax((u64*)&colbest[key_col(k0[k])], tag | k0[k]);
            }
        }
        if (act1) {
            best1 = prune_and_best(k1, coldone);
            if (best1 == 0ull) act1 = false;
            else {
                sub1 = true;
                #pragma unroll
                for (int k = 0; k < TOPK; ++k)
                    if (k1[k] != 0ull)
                        atomicMax((u64*)&colbest[key_col(k1[k])], tag | k1[k]);
            }
        }
        __syncthreads();                          // submissions visible
        u64 cb0 = sub0 ? colbest[key_col(best0)] : 0ull;
        u64 cb1 = sub1 ? colbest[key_col(best1)] : 0ull;
        if (sub0 && cb0 == (tag | best0)) {
            int c = key_col(best0);
            u32 old = atomicOr(&coldone[c >> 5], 1u << (c & 31));
            if (!(old & (1u << (c & 31)))) {
                act[r0] = (float)c;
                atomicOr(&rowdone[r0 >> 5], 1u << (r0 & 31));
                act0 = false;
            }
        }
        if (sub1 && cb1 == (tag | best1)) {
            int c = key_col(best1);
            u32 old = atomicOr(&coldone[c >> 5], 1u << (c & 31));
            if (!(old & (1u << (c & 31)))) {
                act[r1] = (float)c;
                atomicOr(&rowdone[r1 >> 5], 1u << (r1 & 31));
                act1 = false;
            }
        }
        int left = __syncthreads_count((act0 || act1) ? 1 : 0);  // commit barrier
        if (left == 0) break;
    }
    __syncthreads();

    // ---- exact-greedy fallback for exhausted rows (P ~ 1e-7 at depth 16) -----
    if (t < 64) {
        u32 miss = (t < 32) ? ~rowdone[t] : 0u;
        if (__ballot(miss != 0u) != 0ull) {
            for (int guard = 0; guard < 1200; ++guard) {
                u64 best = 0ull;
                for (int rr = 0; rr < MROWS; ++rr) {
                    if ((rowdone[rr >> 5] >> (rr & 31)) & 1u) continue;
                    const float* srow = s + (size_t)rr * NCOLS;
                    u64 rp = (u64)(MROWS - 1 - rr) << 12;
                    for (int c = t; c < NCOLS; c += 64) {
                        if ((coldone[c >> 5] >> (c & 31)) & 1u) continue;
                        u64 kk = ((u64)fkey(__float_as_uint(srow[c])) << 22) | rp |
                                 (u64)(NCOLS - 1 - c);
                        best = umax64(best, kk);
                    }
                }
                best = wave_max_u64(best);
                if (best == 0ull) break;
                if (t == 0) {
                    int row = key_row(best), col = key_col(best);
                    rowdone[row >> 5] |= 1u << (row & 31);
                    coldone[col >> 5] |= 1u << (col & 31);
                    act[row] = (float)col;
                }
                WAVE_FENCE();
            }
        }
    }
    __syncthreads();
    actions[t] = act[t];
    actions[t + 512] = act[t + 512];
}

extern "C" void kernel_launch(void* const* d_in, const int* in_sizes, int n_in,
                              void* d_out, int out_size, void* d_ws, size_t ws_size,
                              hipStream_t stream) {
    (void)in_sizes; (void)n_in; (void)out_size; (void)ws_size;
    const float* scores = (const float*)d_in[0];
    const int* cont = (const int*)d_in[1];
    const int* prev = (const int*)d_in[2];
    float* out = (float*)d_out;
    float* actions = out;
    float* policy = out + MROWS;

    char* ws = (char*)d_ws;
    float* rowsum = (float*)(ws + 0);            // 1024 f
    u32* ready = (u32*)(ws + 4096);              // 1 u32 (zeroed below)
    u64* keys16 = (u64*)(ws + 8192);             // 1024*16 u64 = 128 KiB

    hipMemsetAsync(ready, 0, 4, stream);
    k_rowsum<<<MROWS, 256, 0, stream>>>(scores, rowsum);
    k_main<<<MROWS + 1, 512, 0, stream>>>(scores, cont, prev, rowsum, ready,
                                          keys16, policy, actions);
}

// Round 8
// 91.692 us; speedup vs baseline: 1.7488x; 1.7488x over previous
//
#include <hip/hip_runtime.h>
#include <cstdint>
#include <cstddef>

#define MROWS 1024
#define NCOLS 4096
#define KCAP 32

typedef unsigned long long u64;
typedef unsigned int u32;

// Order-preserving float->u32 map (total order, matches score order exactly).
__device__ inline u32 fkey(u32 b) { return (b & 0x80000000u) ? ~b : (b | 0x80000000u); }

// key = (ord << 22) | ((1023-row) << 12) | (4095-col)   (54 bits used)
__device__ inline int key_col(u64 k) { return (NCOLS - 1) - (int)(k & 0xFFFull); }
__device__ inline int key_row(u64 k) { return (MROWS - 1) - (int)((k >> 12) & 0x3FFull); }

// single-wave LDS ordering fence: wait LDS only, do NOT drain vmcnt
#define WAVE_FENCE() __asm__ volatile("s_waitcnt lgkmcnt(0)" ::: "memory")

__device__ inline float wave_sum_f(float v) {
    #pragma unroll
    for (int off = 32; off >= 1; off >>= 1)
        v += __shfl_xor(v, off, 64);
    return v;
}
__device__ inline u64 wave_max_u64(u64 v) {
    #pragma unroll
    for (int off = 32; off >= 1; off >>= 1) {
        u64 o = __shfl_xor(v, off, 64);
        v = o > v ? o : v;
    }
    return v;
}
__device__ inline u64 umax64(u64 a, u64 b) { return a > b ? a : b; }

// ---------------- K1: per-row threshold key-set + exp-sum ---------------------
// The match only needs each row's stored keys to be an exact PREFIX of the
// row's descending key order. {keys: score > T} is such a prefix for any T
// (fkey monotone; ties cannot straddle T). So: no sort, no top-K passes --
// just collect survivors of a threshold. Ladder 2.5/2.9/3.4/4.2 handles
// overflow (count monotone in T); a short or even empty prefix is still
// exact (row exhausts -> exact fallback in K2). N(0,1): E[count@2.5]~25.
__global__ __launch_bounds__(256) void k_prep(const float* __restrict__ s,
                                              float* __restrict__ rowsum,
                                              u64* __restrict__ keys_g) {
    __shared__ float fred[4];
    __shared__ u64 list[KCAP];
    __shared__ u32 cnt;
    int r = blockIdx.x, t = threadIdx.x;

    const float4* s4 = (const float4*)(s + (size_t)r * NCOLS);
    float4 v0 = s4[t], v1 = s4[t + 256], v2 = s4[t + 512], v3 = s4[t + 768];
    if (t == 0) cnt = 0;

    float se[16] = {v0.x, v0.y, v0.z, v0.w, v1.x, v1.y, v1.z, v1.w,
                    v2.x, v2.y, v2.z, v2.w, v3.x, v3.y, v3.z, v3.w};
    float acc = 0.0f;
    #pragma unroll
    for (int i = 0; i < 16; ++i) acc += __expf(se[i]);
    acc = wave_sum_f(acc);
    if ((t & 63) == 0) fred[t >> 6] = acc;

    u64 rowpart = (u64)(MROWS - 1 - r) << 12;
    __syncthreads();   // cnt=0 and fred visible

    for (int attempt = 0; attempt < 4; ++attempt) {
        float T = attempt == 0 ? 2.5f : attempt == 1 ? 2.9f
                : attempt == 2 ? 3.4f : 4.2f;
        #pragma unroll
        for (int i = 0; i < 16; ++i) {
            if (se[i] > T) {
                u32 slot = atomicAdd(&cnt, 1u);
                if (slot < KCAP) {
                    int c = 4 * (t + (i >> 2) * 256) + (i & 3);
                    list[slot] = ((u64)fkey(__float_as_uint(se[i])) << 22) | rowpart |
                                 (u64)(NCOLS - 1 - c);
                }
            }
        }
        __syncthreads();
        if (cnt <= KCAP) break;        // uniform: collected set is exact prefix
        __syncthreads();               // all threads read cnt before reset
        if (t == 0) cnt = 0;
        __syncthreads();
    }
    u32 n = cnt;
    if (n > KCAP) n = 0;               // ladder failed (adversarial): empty prefix
    if (t < KCAP)                      // transposed: keys_g[slot][row] for K2 coalescing
        keys_g[(size_t)t * MROWS + r] = (t < n) ? list[t] : 0ull;
    if (t == 0) rowsum[r] = fred[0] + fred[1] + fred[2] + fred[3];
}

// ---------------- K2: block 0 = match (parallel rounds); rest = policy --------
// Match: dominant-edge rounds, 1024 threads x 1 row, 32 keys (unsorted
// threshold prefix) in registers; identical to serial greedy since keys are
// distinct u64 and each stored set is an exact prefix; colbest tagged by round.
__global__ __launch_bounds__(1024, 1) void k_policy_match(const float* __restrict__ s,
                                                          const int* __restrict__ cont,
                                                          const int* __restrict__ prev,
                                                          const float* __restrict__ rowsum,
                                                          const u64* __restrict__ keys_g,
                                                          float* __restrict__ policy,
                                                          float* __restrict__ actions) {
    __shared__ u64 colbest[NCOLS];             // 32 KiB (match only)
    __shared__ u32 coldone[NCOLS / 32];        // 512 B
    __shared__ u32 rowdone[MROWS / 32];        // 128 B
    __shared__ float act[MROWS];               // 4 KiB
    __shared__ float fredf[16];

    int t = threadIdx.x;

    if (blockIdx.x != 0) {
        // ---------------- policy row write (1024 thr, 1 float4/thr) -----------
        int r = blockIdx.x - 1;
        const float4* srow4 = (const float4*)(s + (size_t)r * NCOLS);
        float4 v = srow4[t];                   // issue early; flies during reduce
        float sv = rowsum[t];                  // 1024 partials, one per thread
        sv = wave_sum_f(sv);
        if ((t & 63) == 0) fredf[t >> 6] = sv;
        __syncthreads();
        float g = 0.0f;
        #pragma unroll
        for (int i = 0; i < 16; ++i) g += fredf[i];   // same order every block
        float inv = 1.0f / g;
        float4* prow4 = (float4*)(policy + (size_t)r * NCOLS);
        float4 p;
        p.x = __expf(v.x) * inv;
        p.y = __expf(v.y) * inv;
        p.z = __expf(v.z) * inv;
        p.w = __expf(v.w) * inv;
        prow4[t] = p;
        return;
    }

    // ---------------- match: thread t owns row t ------------------------------
    #pragma unroll
    for (int i = 0; i < 4; ++i) colbest[t + i * 1024] = 0ull;
    if (t < 128) coldone[t] = 0u;
    if (t < 32) rowdone[t] = 0u;
    __syncthreads();   // zeroing ordered before the atomics below

    int cgf = cont[t];
    int pv_ = prev[t];
    act[t] = cgf ? (float)pv_ : -1.0f;
    if (cgf) {
        atomicOr(&rowdone[t >> 5], 1u << (t & 31));
        atomicOr(&coldone[pv_ >> 5], 1u << (pv_ & 31));
    }
    bool active = (cgf == 0);

    u64 kk[KCAP];
    #pragma unroll
    for (int k = 0; k < KCAP; ++k) kk[k] = keys_g[(size_t)k * MROWS + t];
    __syncthreads();

    for (int round = 1; round < 400; ++round) {
        u64 tag = (u64)round << 54;
        bool sub = false;
        u64 best = 0ull;
        if (active) {
            // prune in two 16-key batches (batched coldone loads, low VGPR)
            #pragma unroll
            for (int h = 0; h < 2; ++h) {
                u32 cw[16];
                #pragma unroll
                for (int k = 0; k < 16; ++k) {
                    int c = key_col(kk[h * 16 + k]);   // dead key -> col 4095, safe
                    cw[k] = coldone[c >> 5];
                }
                #pragma unroll
                for (int k = 0; k < 16; ++k) {
                    int c = key_col(kk[h * 16 + k]);
                    if ((cw[k] >> (c & 31)) & 1u) kk[h * 16 + k] = 0ull;
                    best = umax64(best, kk[h * 16 + k]);
                }
            }
            if (best == 0ull) {
                active = false;                 // exhausted -> exact fallback
            } else {
                sub = true;
                #pragma unroll
                for (int k = 0; k < KCAP; ++k)
                    if (kk[k] != 0ull)
                        atomicMax((u64*)&colbest[key_col(kk[k])], tag | kk[k]);
            }
        }
        __syncthreads();                        // submissions visible
        if (sub && colbest[key_col(best)] == (tag | best)) {
            int c = key_col(best);
            u32 old = atomicOr(&coldone[c >> 5], 1u << (c & 31));
            if (!(old & (1u << (c & 31)))) {
                act[t] = (float)c;
                atomicOr(&rowdone[t >> 5], 1u << (t & 31));
                active = false;
            }
        }
        int left = __syncthreads_count(active ? 1 : 0);   // commits visible
        if (left == 0) break;
    }
    __syncthreads();

    // ---- exact-greedy fallback for exhausted rows (rare) ---------------------
    if (t < 64) {
        u32 miss = (t < 32) ? ~rowdone[t] : 0u;
        if (__ballot(miss != 0u) != 0ull) {
            for (int guard = 0; guard < 1200; ++guard) {
                u64 best = 0ull;
                for (int rr = 0; rr < MROWS; ++rr) {
                    if ((rowdone[rr >> 5] >> (rr & 31)) & 1u) continue;
                    const float* srow = s + (size_t)rr * NCOLS;
                    u64 rp = (u64)(MROWS - 1 - rr) << 12;
                    for (int c = t; c < NCOLS; c += 64) {
                        if ((coldone[c >> 5] >> (c & 31)) & 1u) continue;
                        u64 kk2 = ((u64)fkey(__float_as_uint(srow[c])) << 22) | rp |
                                  (u64)(NCOLS - 1 - c);
                        best = umax64(best, kk2);
                    }
                }
                best = wave_max_u64(best);
                if (best == 0ull) break;
                if (t == 0) {
                    int row = key_row(best), col = key_col(best);
                    rowdone[row >> 5] |= 1u << (row & 31);
                    coldone[col >> 5] |= 1u << (col & 31);
                    act[row] = (float)col;
                }
                WAVE_FENCE();
            }
        }
    }
    __syncthreads();
    actions[t] = act[t];
}

extern "C" void kernel_launch(void* const* d_in, const int* in_sizes, int n_in,
                              void* d_out, int out_size, void* d_ws, size_t ws_size,
                              hipStream_t stream) {
    (void)in_sizes; (void)n_in; (void)out_size; (void)ws_size;
    const float* scores = (const float*)d_in[0];
    const int* cont = (const int*)d_in[1];
    const int* prev = (const int*)d_in[2];
    float* out = (float*)d_out;
    float* actions = out;
    float* policy = out + MROWS;

    char* ws = (char*)d_ws;
    float* rowsum = (float*)(ws + 0);            // 1024 f
    u64* keys32 = (u64*)(ws + 8192);             // 32*1024 u64 = 256 KiB (transposed)

    k_prep<<<MROWS, 256, 0, stream>>>(scores, rowsum, keys32);
    k_policy_match<<<MROWS + 1, 1024, 0, stream>>>(scores, cont, prev, rowsum,
                                                   keys32, policy, actions);
}